// Round 5
// baseline (884.209 us; speedup 1.0000x reference)
//
#include <hip/hip_runtime.h>

#define U_N 100000
#define I_N 50000
#define N_NODES 150000
#define EMB_D 64
#define NNZ 4800000
#define ND (N_NODES * EMB_D)          /* 9,600,000 */
#define ND4 (ND / 4)
#define UD4 (U_N * EMB_D / 4)

#define RPB 1024                              /* rows per bucket */
#define NB ((N_NODES + RPB - 1) / RPB)        /* 147 buckets */
#define TILE 4096                             /* edges per tile */
#define NTILE ((NNZ + TILE - 1) / TILE)       /* 1172 */

#define SCB 1024                              /* rows per scan block */
#define NSB ((N_NODES + SCB - 1) / SCB)       /* 147; 147*1024=150,528 padded */
#define NQ4 (NNZ / 4)                         /* 1,200,000 edge quads */

__device__ __forceinline__ unsigned short f2bf(float f) {
    unsigned int u = __float_as_uint(f);
    unsigned int r = (u + 0x7FFFu + ((u >> 16) & 1u)) >> 16;
    return (unsigned short)r;
}
__device__ __forceinline__ float bf2f(unsigned short h) {
    return __uint_as_float((unsigned int)h << 16);
}

// emb0 = concat(u,i); hb0 = bf16(emb0)
__global__ void k_init(const float4* __restrict__ u, const float4* __restrict__ it,
                       float4* __restrict__ emb0, ushort4* __restrict__ hb0) {
    int i = blockIdx.x * blockDim.x + threadIdx.x;
    if (i >= ND4) return;
    float4 v = (i < UD4) ? u[i] : it[i - UD4];
    emb0[i] = v;
    ushort4 h;
    h.x = f2bf(v.x); h.y = f2bf(v.y); h.z = f2bf(v.z); h.w = f2bf(v.w);
    hb0[i] = h;
}

// ---- per-row histogram: fire-and-forget global atomics, int4 loads ----
__global__ void k_row_hist(const int4* __restrict__ row4, int* __restrict__ rcount) {
    int i = blockIdx.x * blockDim.x + threadIdx.x;
    if (i >= NQ4) return;
    int4 r = row4[i];
    atomicAdd(&rcount[r.x], 1);
    atomicAdd(&rcount[r.y], 1);
    atomicAdd(&rcount[r.z], 1);
    atomicAdd(&rcount[r.w], 1);
}

// ---- scan stage 1: per-block sums of 1024 counts (int4 loads, wave reduce)
__global__ void k_block_sums(const int4* __restrict__ rcount4, int* __restrict__ bsum) {
    __shared__ int wsum[4];
    int b = blockIdx.x, t = threadIdx.x;
    int lane = t & 63, wv = t >> 6;
    int4 r = rcount4[b * 256 + t];                  // covers exactly 147*1024 ints
    int s = r.x + r.y + r.z + r.w;
    for (int off = 32; off > 0; off >>= 1) s += __shfl_down(s, off);
    if (lane == 0) wsum[wv] = s;
    __syncthreads();
    if (t == 0) bsum[b] = wsum[0] + wsum[1] + wsum[2] + wsum[3];
}

// ---- scan stage 2: exclusive scan of NSB (=147) block sums
__global__ void k_scan_bsum(const int* __restrict__ bsum, int* __restrict__ bbase) {
    __shared__ int wsum[4];
    int t = threadIdx.x, lane = t & 63, wv = t >> 6;
    int v = (t < NSB) ? bsum[t] : 0;
    int iv = v;
    for (int off = 1; off < 64; off <<= 1) {
        int u = __shfl_up(iv, off);
        if (lane >= off) iv += u;
    }
    if (lane == 63) wsum[wv] = iv;
    __syncthreads();
    int woff = 0;
    for (int w = 0; w < wv; ++w) woff += wsum[w];
    if (t < NSB) bbase[t] = woff + iv - v;
}

// ---- scan stage 3: full exclusive row scan -> rp, row cursors, bucket cursors
__global__ void k_scan_rows(const int* __restrict__ rcount, const int* __restrict__ bbase,
                            int* __restrict__ rp, int* __restrict__ cur,
                            int* __restrict__ bcur) {
    __shared__ int wsum[16];
    int b = blockIdx.x, t = threadIdx.x;
    int lane = t & 63, wv = t >> 6;
    int gid = b * SCB + t;
    int v = rcount[gid];                            // padded region is zeroed
    int iv = v;
    for (int off = 1; off < 64; off <<= 1) {
        int u = __shfl_up(iv, off);
        if (lane >= off) iv += u;
    }
    if (lane == 63) wsum[wv] = iv;
    __syncthreads();
    int woff = 0;
    for (int w = 0; w < wv; ++w) woff += wsum[w];
    int ex = bbase[b] + woff + iv - v;
    if (gid <= N_NODES) rp[gid] = ex;               // rp[N_NODES] = NNZ (zero pad)
    if (gid < N_NODES) cur[gid] = ex;
    if (t == 0) bcur[b] = ex;                       // bucket b starts at row b*1024
}

// ---------------- phase A: LDS-staged partition into 147 buckets ------------
// tmp[p] = { (row_local<<18)|col , val_bits } grouped (unordered) by bucket
// (round-2 verified config: TILE=4096, 16 edges/thread, uchar stageB)
__global__ void k_partition(const int* __restrict__ row, const int* __restrict__ col,
                            const float* __restrict__ vals, int* __restrict__ bcur,
                            int2* __restrict__ tmp) {
    __shared__ int2 stage[TILE];
    __shared__ unsigned char stageB[TILE];
    __shared__ int hist[NB];
    __shared__ int scn[NB];
    __shared__ int gbase[NB];
    __shared__ int wsum[4];
    int t = threadIdx.x;
    int lane = t & 63, wv = t >> 6;
    for (int i = t; i < NB; i += 256) hist[i] = 0;
    __syncthreads();
    int base = blockIdx.x * TILE;
    int cnt = min(TILE, NNZ - base);

    int  myb[16];
    int  myslot[16];
    int2 myp[16];
#pragma unroll
    for (int j = 0; j < 16; ++j) {
        int i = t + j * 256;
        myb[j] = -1;
        if (i < cnt) {
            int e = base + i;
            int r = row[e];
            int b = r >> 10;
            myb[j] = b;
            myp[j] = make_int2(((r & (RPB - 1)) << 18) | col[e], __float_as_int(vals[e]));
            myslot[j] = atomicAdd(&hist[b], 1);
        }
    }
    __syncthreads();
    // wave-shuffle exclusive scan of hist -> scn (2 barriers total, NB<=256)
    int v = (t < NB) ? hist[t] : 0;
    int iv = v;
    for (int off = 1; off < 64; off <<= 1) {
        int u = __shfl_up(iv, off);
        if (lane >= off) iv += u;
    }
    if (lane == 63) wsum[wv] = iv;
    __syncthreads();
    int woff = 0;
    for (int w = 0; w < wv; ++w) woff += wsum[w];
    if (t < NB) scn[t] = woff + iv - v;
    if (t < NB && v > 0) gbase[t] = atomicAdd(&bcur[t], v);
    __syncthreads();
#pragma unroll
    for (int j = 0; j < 16; ++j) {
        if (myb[j] >= 0) {
            int pos = scn[myb[j]] + myslot[j];
            stage[pos] = myp[j];
            stageB[pos] = (unsigned char)myb[j];
        }
    }
    __syncthreads();
    for (int i = t; i < cnt; i += 256) {
        int b = stageB[i];
        tmp[gbase[b] + (i - scn[b])] = stage[i];
    }
}

// ---------------- phase B: single-pass exact placement ----------------------
// Streams bucket-grouped tmp once; bucket recovered from rp[b*1024] boundaries
// (monotone walk); exact slot via atomicAdd on per-row cursor. Writes land in
// the 1-2 bucket windows (<=0.5 MB) this block's slice spans -> L2-coalesced.
__global__ void k_place(const int* __restrict__ rp, const int2* __restrict__ tmp,
                        int* __restrict__ cur, int2* __restrict__ edges) {
    __shared__ int bb[NB + 1];
    int t = threadIdx.x;
    for (int j = t; j <= NB; j += 256) bb[j] = rp[min(j * RPB, N_NODES)];
    __syncthreads();
    int base = blockIdx.x * TILE;
    int cnt = min(TILE, NNZ - base);
    if (t >= cnt) return;
    int2 E[16];
#pragma unroll
    for (int j = 0; j < 16; ++j) {
        int i = t + j * 256;
        if (i < cnt) E[j] = tmp[base + i];
    }
    // initial bucket for this thread's first edge (binary search in LDS)
    int g0 = base + t;
    int lo = 0, hi = NB - 1;
    while (lo < hi) {
        int mid = (lo + hi) >> 1;
        if (bb[mid + 1] <= g0) lo = mid + 1; else hi = mid;
    }
    int b = lo;
    int pos[16];
#pragma unroll
    for (int j = 0; j < 16; ++j) {
        int i = t + j * 256;
        if (i < cnt) {
            int g = base + i;
            while (g >= bb[b + 1]) ++b;             // monotone, amortized O(NB)
            int r = (b << 10) + ((unsigned)E[j].x >> 18);
            pos[j] = atomicAdd(&cur[r], 1);
        }
    }
#pragma unroll
    for (int j = 0; j < 16; ++j) {
        int i = t + j * 256;
        if (i < cnt)
            edges[pos[j]] = make_int2(E[j].x & 0x3FFFF, E[j].y);
    }
}

// ---------------- pull SpMM, one wave per row, lane = dim, bf16 gather ------
__device__ __forceinline__ float row_dot(const int* __restrict__ rp,
                                         const int2* __restrict__ edges,
                                         const unsigned short* __restrict__ x,
                                         int wid, int lane) {
    int start = __builtin_amdgcn_readfirstlane(rp[wid]);
    int end   = __builtin_amdgcn_readfirstlane(rp[wid + 1]);
    float s0 = 0.f, s1 = 0.f, s2 = 0.f, s3 = 0.f;
    int e = start;
    for (; e + 16 <= end; e += 16) {
        int2 E[16];
#pragma unroll
        for (int j = 0; j < 16; ++j) E[j] = edges[e + j];
        float g[16];
#pragma unroll
        for (int j = 0; j < 16; ++j) g[j] = bf2f(x[(size_t)E[j].x * EMB_D + lane]);
#pragma unroll
        for (int j = 0; j < 16; ++j) {
            float p = __int_as_float(E[j].y) * g[j];
            if ((j & 3) == 0) s0 += p;
            else if ((j & 3) == 1) s1 += p;
            else if ((j & 3) == 2) s2 += p;
            else s3 += p;
        }
    }
    int rem = end - e;
    if (rem > 0) {
        // over-reads <=15 int2 past rp[N]; lands in allocated ws, masked below
        int2 E[16];
#pragma unroll
        for (int j = 0; j < 16; ++j) E[j] = edges[e + j];
#pragma unroll
        for (int j = 0; j < 16; ++j)
            if (j >= rem) { E[j].x = 0; E[j].y = 0; }
        float g[16];
#pragma unroll
        for (int j = 0; j < 16; ++j) g[j] = bf2f(x[(size_t)E[j].x * EMB_D + lane]);
#pragma unroll
        for (int j = 0; j < 16; ++j) {
            float p = __int_as_float(E[j].y) * g[j];
            if ((j & 3) == 0) s0 += p;
            else if ((j & 3) == 1) s1 += p;
            else if ((j & 3) == 2) s2 += p;
            else s3 += p;
        }
    }
    return (s0 + s1) + (s2 + s3);
}

// layers 1,2: y = bf16(spmm(x)) only
__global__ void k_spmm_mid(const int* __restrict__ rp, const int2* __restrict__ edges,
                           const unsigned short* __restrict__ x,
                           unsigned short* __restrict__ y) {
    int wid = blockIdx.x * (blockDim.x >> 6) + (threadIdx.x >> 6);
    if (wid >= N_NODES) return;
    int lane = threadIdx.x & 63;
    float s = row_dot(rp, edges, x, wid, lane);
    y[(size_t)wid * EMB_D + lane] = f2bf(s);
}

// layer 3: acc = (emb0 + y1 + y2 + s) * 0.25
__global__ void k_spmm_fin(const int* __restrict__ rp, const int2* __restrict__ edges,
                           const unsigned short* __restrict__ x,
                           const float* __restrict__ emb0,
                           const unsigned short* __restrict__ y1,
                           const unsigned short* __restrict__ y2,
                           float* __restrict__ acc) {
    int wid = blockIdx.x * (blockDim.x >> 6) + (threadIdx.x >> 6);
    if (wid >= N_NODES) return;
    int lane = threadIdx.x & 63;
    float s = row_dot(rp, edges, x, wid, lane);
    size_t o = (size_t)wid * EMB_D + lane;
    acc[o] = (emb0[o] + bf2f(y1[o]) + bf2f(y2[o]) + s) * 0.25f;
}

extern "C" void kernel_launch(void* const* d_in, const int* in_sizes, int n_in,
                              void* d_out, int out_size, void* d_ws, size_t ws_size,
                              hipStream_t stream) {
    const float* user_emb = (const float*)d_in[0];
    const float* item_emb = (const float*)d_in[1];
    const int*   row      = (const int*)d_in[2];
    const int*   col      = (const int*)d_in[3];
    const float* vals     = (const float*)d_in[4];

    float* emb0 = (float*)d_out;            // [ND] output 0
    float* acc  = (float*)d_out + ND;       // [ND] output 1

    // ws: [tmp int2[NNZ] | edges int2[NNZ] | hb2 ushort[ND] | ints]
    // tmp (38.4 MB) is dead after k_place -> reused as hb0/hb1 bf16
    int2* tmp   = (int2*)d_ws;
    int2* edges = tmp + NNZ;
    unsigned short* hb2 = (unsigned short*)(edges + NNZ);   // [ND]
    int* rcount = (int*)(hb2 + ND);          // [NSB*SCB] padded, zeroed
    int* rp     = rcount + NSB * SCB;        // [N_NODES+1]
    int* cur    = rp + N_NODES + 1;          // [N_NODES]
    int* bcur   = cur + N_NODES;             // [NB]
    int* bsum   = bcur + NB;                 // [NSB]
    int* bbase  = bsum + NSB;                // [NSB]
    unsigned short* hb0 = (unsigned short*)d_ws;   // [ND] aliases tmp
    unsigned short* hb1 = hb0 + ND;                // [ND]

    const int BLK = 256;
    const int grid_nd = (ND4 + BLK - 1) / BLK;
    const int grid_q4 = (NQ4 + BLK - 1) / BLK;
    const int grid_spmm = (N_NODES * 64 + BLK - 1) / BLK;  // 1 wave per row

    // --- counts first: hist -> 3-stage scan (rp + row/bucket cursors) ---
    hipMemsetAsync(rcount, 0, NSB * SCB * sizeof(int), stream);
    k_row_hist<<<grid_q4, BLK, 0, stream>>>((const int4*)row, rcount);
    k_block_sums<<<NSB, BLK, 0, stream>>>((const int4*)rcount, bsum);
    k_scan_bsum<<<1, BLK, 0, stream>>>(bsum, bbase);
    k_scan_rows<<<NSB, SCB, 0, stream>>>(rcount, bbase, rp, cur, bcur);

    // --- movement: bucket-partition then single-pass exact placement ---
    k_partition<<<NTILE, BLK, 0, stream>>>(row, col, vals, bcur, tmp);
    k_place<<<NTILE, BLK, 0, stream>>>(rp, tmp, cur, edges);

    // --- init outputs + bf16 layer-0 (overwrites tmp region) ---
    k_init<<<grid_nd, BLK, 0, stream>>>((const float4*)user_emb,
                                        (const float4*)item_emb,
                                        (float4*)emb0, (ushort4*)hb0);

    // --- 3 propagation layers, acc deferred to the final pass ---
    k_spmm_mid<<<grid_spmm, BLK, 0, stream>>>(rp, edges, hb0, hb1);
    k_spmm_mid<<<grid_spmm, BLK, 0, stream>>>(rp, edges, hb1, hb2);
    k_spmm_fin<<<grid_spmm, BLK, 0, stream>>>(rp, edges, hb2, emb0, hb1, hb2, acc);
}

// Round 6
// 724.956 us; speedup vs baseline: 1.2197x; 1.2197x over previous
//
#include <hip/hip_runtime.h>

#define U_N 100000
#define I_N 50000
#define N_NODES 150000
#define EMB_D 64
#define NNZ 4800000
#define ND (N_NODES * EMB_D)          /* 9,600,000 */
#define ND4 (ND / 4)
#define UD4 (U_N * EMB_D / 4)

#define RPB 1024                              /* rows per bucket */
#define NB ((N_NODES + RPB - 1) / RPB)        /* 147 buckets */
#define TILE 4096                             /* edges per partition tile */
#define NTILE ((NNZ + TILE - 1) / TILE)       /* 1172 */

#define SCB 1024                              /* rows per scan block (== RPB) */
#define NSB ((N_NODES + SCB - 1) / SCB)       /* 147; 147*1024=150,528 padded */
#define NQ4 (NNZ / 4)                         /* 1,200,000 edge quads */

__device__ __forceinline__ unsigned short f2bf(float f) {
    unsigned int u = __float_as_uint(f);
    unsigned int r = (u + 0x7FFFu + ((u >> 16) & 1u)) >> 16;
    return (unsigned short)r;
}
__device__ __forceinline__ float bf2f(unsigned short h) {
    return __uint_as_float((unsigned int)h << 16);
}

// emb0 = concat(u,i); hb0 = bf16(emb0)
__global__ void k_init(const float4* __restrict__ u, const float4* __restrict__ it,
                       float4* __restrict__ emb0, ushort4* __restrict__ hb0) {
    int i = blockIdx.x * blockDim.x + threadIdx.x;
    if (i >= ND4) return;
    float4 v = (i < UD4) ? u[i] : it[i - UD4];
    emb0[i] = v;
    ushort4 h;
    h.x = f2bf(v.x); h.y = f2bf(v.y); h.z = f2bf(v.z); h.w = f2bf(v.w);
    hb0[i] = h;
}

// ---- per-row histogram: fire-and-forget global atomics, int4 loads ----
__global__ void k_row_hist(const int4* __restrict__ row4, int* __restrict__ rcount) {
    int i = blockIdx.x * blockDim.x + threadIdx.x;
    if (i >= NQ4) return;
    int4 r = row4[i];
    atomicAdd(&rcount[r.x], 1);
    atomicAdd(&rcount[r.y], 1);
    atomicAdd(&rcount[r.z], 1);
    atomicAdd(&rcount[r.w], 1);
}

// ---- scan stage 1: per-block sums of 1024 counts (int4 loads, wave reduce)
__global__ void k_block_sums(const int4* __restrict__ rcount4, int* __restrict__ bsum) {
    __shared__ int wsum[4];
    int b = blockIdx.x, t = threadIdx.x;
    int lane = t & 63, wv = t >> 6;
    int4 r = rcount4[b * 256 + t];                  // covers exactly 147*1024 ints
    int s = r.x + r.y + r.z + r.w;
    for (int off = 32; off > 0; off >>= 1) s += __shfl_down(s, off);
    if (lane == 0) wsum[wv] = s;
    __syncthreads();
    if (t == 0) bsum[b] = wsum[0] + wsum[1] + wsum[2] + wsum[3];
}

// ---- scan stage 2: exclusive scan of NSB (=147) block sums
__global__ void k_scan_bsum(const int* __restrict__ bsum, int* __restrict__ bbase) {
    __shared__ int wsum[4];
    int t = threadIdx.x, lane = t & 63, wv = t >> 6;
    int v = (t < NSB) ? bsum[t] : 0;
    int iv = v;
    for (int off = 1; off < 64; off <<= 1) {
        int u = __shfl_up(iv, off);
        if (lane >= off) iv += u;
    }
    if (lane == 63) wsum[wv] = iv;
    __syncthreads();
    int woff = 0;
    for (int w = 0; w < wv; ++w) woff += wsum[w];
    if (t < NSB) bbase[t] = woff + iv - v;
}

// ---- scan stage 3: full exclusive row scan -> rp + bucket cursors for partition
__global__ void k_scan_rows(const int* __restrict__ rcount, const int* __restrict__ bbase,
                            int* __restrict__ rp, int* __restrict__ bcur) {
    __shared__ int wsum[16];
    int b = blockIdx.x, t = threadIdx.x;
    int lane = t & 63, wv = t >> 6;
    int gid = b * SCB + t;
    int v = rcount[gid];                            // padded region is zeroed
    int iv = v;
    for (int off = 1; off < 64; off <<= 1) {
        int u = __shfl_up(iv, off);
        if (lane >= off) iv += u;
    }
    if (lane == 63) wsum[wv] = iv;
    __syncthreads();
    int woff = 0;
    for (int w = 0; w < wv; ++w) woff += wsum[w];
    int ex = bbase[b] + woff + iv - v;
    if (gid <= N_NODES) rp[gid] = ex;               // rp[N_NODES] = NNZ (zero pad)
    if (t == 0) bcur[b] = ex;                       // bucket b starts at row b*1024
}

// ---------------- phase A: LDS-staged partition into 147 buckets ------------
// tmp[p] = { (row_local<<18)|col , val_bits } grouped (unordered) by bucket
// (round-2 verified config: TILE=4096, 16 edges/thread, uchar stageB)
__global__ void k_partition(const int* __restrict__ row, const int* __restrict__ col,
                            const float* __restrict__ vals, int* __restrict__ bcur,
                            int2* __restrict__ tmp) {
    __shared__ int2 stage[TILE];
    __shared__ unsigned char stageB[TILE];
    __shared__ int hist[NB];
    __shared__ int scn[NB];
    __shared__ int gbase[NB];
    __shared__ int wsum[4];
    int t = threadIdx.x;
    int lane = t & 63, wv = t >> 6;
    for (int i = t; i < NB; i += 256) hist[i] = 0;
    __syncthreads();
    int base = blockIdx.x * TILE;
    int cnt = min(TILE, NNZ - base);

    int  myb[16];
    int  myslot[16];
    int2 myp[16];
#pragma unroll
    for (int j = 0; j < 16; ++j) {
        int i = t + j * 256;
        myb[j] = -1;
        if (i < cnt) {
            int e = base + i;
            int r = row[e];
            int b = r >> 10;
            myb[j] = b;
            myp[j] = make_int2(((r & (RPB - 1)) << 18) | col[e], __float_as_int(vals[e]));
            myslot[j] = atomicAdd(&hist[b], 1);
        }
    }
    __syncthreads();
    // wave-shuffle exclusive scan of hist -> scn (2 barriers total, NB<=256)
    int v = (t < NB) ? hist[t] : 0;
    int iv = v;
    for (int off = 1; off < 64; off <<= 1) {
        int u = __shfl_up(iv, off);
        if (lane >= off) iv += u;
    }
    if (lane == 63) wsum[wv] = iv;
    __syncthreads();
    int woff = 0;
    for (int w = 0; w < wv; ++w) woff += wsum[w];
    if (t < NB) scn[t] = woff + iv - v;
    if (t < NB && v > 0) gbase[t] = atomicAdd(&bcur[t], v);
    __syncthreads();
#pragma unroll
    for (int j = 0; j < 16; ++j) {
        if (myb[j] >= 0) {
            int pos = scn[myb[j]] + myslot[j];
            stage[pos] = myp[j];
            stageB[pos] = (unsigned char)myb[j];
        }
    }
    __syncthreads();
    for (int i = t; i < cnt; i += 256) {
        int b = stageB[i];
        tmp[gbase[b] + (i - scn[b])] = stage[i];
    }
}

// ---------------- phase B: single-pass placement, one block per bucket ------
// Per-row cursors come straight from rp (no counting pass). One block owns the
// whole bucket's write window -> partial lines coalesce in ONE L2 (no XCD
// write amplification). Reads tmp once, writes edges once.
__global__ void k_place(const int* __restrict__ rp, const int2* __restrict__ tmp,
                        int2* __restrict__ edges) {
    __shared__ int lex[RPB];
    int b = blockIdx.x, t = threadIdx.x;            // 1024 threads
    int r = b * RPB + t;
    lex[t] = (r < N_NODES) ? rp[r] : NNZ;
    int s0 = rp[b * RPB];
    int s1 = rp[min((b + 1) * RPB, N_NODES)];
    __syncthreads();
    for (int i = s0 + t; i < s1; i += 1024) {
        int2 p = tmp[i];
        int rl = (unsigned)p.x >> 18;
        int pos = atomicAdd(&lex[rl], 1);
        edges[pos] = make_int2(p.x & 0x3FFFF, p.y);
    }
}

// ---------------- pull SpMM, one wave per row, lane = dim, bf16 gather ------
// 16 gathers in flight per wave; edge loads are wave-uniform -> s_load path.
// Tail handled by one masked 16-chunk (col->0, val->0), never a serial loop.
__device__ __forceinline__ float row_dot(const int* __restrict__ rp,
                                         const int2* __restrict__ edges,
                                         const unsigned short* __restrict__ x,
                                         int wid, int lane) {
    int start = __builtin_amdgcn_readfirstlane(rp[wid]);
    int end   = __builtin_amdgcn_readfirstlane(rp[wid + 1]);
    float s0 = 0.f, s1 = 0.f, s2 = 0.f, s3 = 0.f;
    int e = start;
    for (; e + 16 <= end; e += 16) {
        int2 E[16];
#pragma unroll
        for (int j = 0; j < 16; ++j) E[j] = edges[e + j];
        float g[16];
#pragma unroll
        for (int j = 0; j < 16; ++j) g[j] = bf2f(x[(size_t)E[j].x * EMB_D + lane]);
#pragma unroll
        for (int j = 0; j < 16; ++j) {
            float p = __int_as_float(E[j].y) * g[j];
            if ((j & 3) == 0) s0 += p;
            else if ((j & 3) == 1) s1 += p;
            else if ((j & 3) == 2) s2 += p;
            else s3 += p;
        }
    }
    int rem = end - e;
    if (rem > 0) {
        // over-reads <=15 int2 past rp[N]; lands in allocated ws, masked below
        int2 E[16];
#pragma unroll
        for (int j = 0; j < 16; ++j) E[j] = edges[e + j];
#pragma unroll
        for (int j = 0; j < 16; ++j)
            if (j >= rem) { E[j].x = 0; E[j].y = 0; }
        float g[16];
#pragma unroll
        for (int j = 0; j < 16; ++j) g[j] = bf2f(x[(size_t)E[j].x * EMB_D + lane]);
#pragma unroll
        for (int j = 0; j < 16; ++j) {
            float p = __int_as_float(E[j].y) * g[j];
            if ((j & 3) == 0) s0 += p;
            else if ((j & 3) == 1) s1 += p;
            else if ((j & 3) == 2) s2 += p;
            else s3 += p;
        }
    }
    return (s0 + s1) + (s2 + s3);
}

// layers 1,2: y = bf16(spmm(x)) only
__global__ void k_spmm_mid(const int* __restrict__ rp, const int2* __restrict__ edges,
                           const unsigned short* __restrict__ x,
                           unsigned short* __restrict__ y) {
    int wid = blockIdx.x * (blockDim.x >> 6) + (threadIdx.x >> 6);
    if (wid >= N_NODES) return;
    int lane = threadIdx.x & 63;
    float s = row_dot(rp, edges, x, wid, lane);
    y[(size_t)wid * EMB_D + lane] = f2bf(s);
}

// layer 3: acc = (emb0 + y1 + y2 + s) * 0.25
__global__ void k_spmm_fin(const int* __restrict__ rp, const int2* __restrict__ edges,
                           const unsigned short* __restrict__ x,
                           const float* __restrict__ emb0,
                           const unsigned short* __restrict__ y1,
                           const unsigned short* __restrict__ y2,
                           float* __restrict__ acc) {
    int wid = blockIdx.x * (blockDim.x >> 6) + (threadIdx.x >> 6);
    if (wid >= N_NODES) return;
    int lane = threadIdx.x & 63;
    float s = row_dot(rp, edges, x, wid, lane);
    size_t o = (size_t)wid * EMB_D + lane;
    acc[o] = (emb0[o] + bf2f(y1[o]) + bf2f(y2[o]) + s) * 0.25f;
}

extern "C" void kernel_launch(void* const* d_in, const int* in_sizes, int n_in,
                              void* d_out, int out_size, void* d_ws, size_t ws_size,
                              hipStream_t stream) {
    const float* user_emb = (const float*)d_in[0];
    const float* item_emb = (const float*)d_in[1];
    const int*   row      = (const int*)d_in[2];
    const int*   col      = (const int*)d_in[3];
    const float* vals     = (const float*)d_in[4];

    float* emb0 = (float*)d_out;            // [ND] output 0
    float* acc  = (float*)d_out + ND;       // [ND] output 1

    // ws: [tmp int2[NNZ] | edges int2[NNZ] | hb2 ushort[ND] | ints]
    // tmp (38.4 MB) is dead after k_place -> reused as hb0/hb1 bf16
    int2* tmp   = (int2*)d_ws;
    int2* edges = tmp + NNZ;
    unsigned short* hb2 = (unsigned short*)(edges + NNZ);   // [ND]
    int* rcount = (int*)(hb2 + ND);          // [NSB*SCB] padded, zeroed
    int* rp     = rcount + NSB * SCB;        // [N_NODES+1]
    int* bcur   = rp + N_NODES + 1;          // [NB]
    int* bsum   = bcur + NB;                 // [NSB]
    int* bbase  = bsum + NSB;                // [NSB]
    unsigned short* hb0 = (unsigned short*)d_ws;   // [ND] aliases tmp
    unsigned short* hb1 = hb0 + ND;                // [ND]

    const int BLK = 256;
    const int grid_nd = (ND4 + BLK - 1) / BLK;
    const int grid_q4 = (NQ4 + BLK - 1) / BLK;
    const int grid_spmm = (N_NODES * 64 + BLK - 1) / BLK;  // 1 wave per row

    // --- counts first: row hist -> 3-stage scan (rp + bucket cursors) ---
    hipMemsetAsync(rcount, 0, NSB * SCB * sizeof(int), stream);
    k_row_hist<<<grid_q4, BLK, 0, stream>>>((const int4*)row, rcount);
    k_block_sums<<<NSB, BLK, 0, stream>>>((const int4*)rcount, bsum);
    k_scan_bsum<<<1, BLK, 0, stream>>>(bsum, bbase);
    k_scan_rows<<<NSB, SCB, 0, stream>>>(rcount, bbase, rp, bcur);

    // --- movement: bucket-partition, then single-pass per-bucket placement ---
    k_partition<<<NTILE, BLK, 0, stream>>>(row, col, vals, bcur, tmp);
    k_place<<<NB, 1024, 0, stream>>>(rp, tmp, edges);

    // --- init outputs + bf16 layer-0 (overwrites tmp region) ---
    k_init<<<grid_nd, BLK, 0, stream>>>((const float4*)user_emb,
                                        (const float4*)item_emb,
                                        (float4*)emb0, (ushort4*)hb0);

    // --- 3 propagation layers, acc deferred to the final pass ---
    k_spmm_mid<<<grid_spmm, BLK, 0, stream>>>(rp, edges, hb0, hb1);
    k_spmm_mid<<<grid_spmm, BLK, 0, stream>>>(rp, edges, hb1, hb2);
    k_spmm_fin<<<grid_spmm, BLK, 0, stream>>>(rp, edges, hb2, emb0, hb1, hb2, acc);
}

// Round 7
// 570.822 us; speedup vs baseline: 1.5490x; 1.2700x over previous
//
#include <hip/hip_runtime.h>

#define U_N 100000
#define I_N 50000
#define N_NODES 150000
#define EMB_D 64
#define NNZ 4800000
#define ND (N_NODES * EMB_D)          /* 9,600,000 */
#define ND4 (ND / 4)
#define UD4 (U_N * EMB_D / 4)

#define RPB 1024                              /* rows per bucket */
#define NB ((N_NODES + RPB - 1) / RPB)        /* 147 buckets */
#define TILE 4096                             /* edges per partition tile */
#define NTILE ((NNZ + TILE - 1) / TILE)       /* 1172 */
#define HTILE 4096                            /* edges per hist tile */
#define NHT ((NNZ + HTILE - 1) / HTILE)       /* 1172 */

__device__ __forceinline__ unsigned short f2bf(float f) {
    unsigned int u = __float_as_uint(f);
    unsigned int r = (u + 0x7FFFu + ((u >> 16) & 1u)) >> 16;
    return (unsigned short)r;
}
__device__ __forceinline__ float bf2f(unsigned short h) {
    return __uint_as_float((unsigned int)h << 16);
}

// emb0 = concat(u,i); hb0 = bf16(emb0)
__global__ void k_init(const float4* __restrict__ u, const float4* __restrict__ it,
                       float4* __restrict__ emb0, ushort4* __restrict__ hb0) {
    int i = blockIdx.x * blockDim.x + threadIdx.x;
    if (i >= ND4) return;
    float4 v = (i < UD4) ? u[i] : it[i - UD4];
    emb0[i] = v;
    ushort4 h;
    h.x = f2bf(v.x); h.y = f2bf(v.y); h.z = f2bf(v.z); h.w = f2bf(v.w);
    hb0[i] = h;
}

// ---------------- bucket histogram (LDS-staged, privatized, int4) ----------
__global__ void k_bucket_hist(const int4* __restrict__ row4, int* __restrict__ bhist) {
    __shared__ int lh[4][NB];                       // per-wave copies
    int t = threadIdx.x, wv = t >> 6;               // 4 waves
    for (int i = t; i < 4 * NB; i += 256) ((int*)lh)[i] = 0;
    __syncthreads();
    int base = blockIdx.x * (HTILE / 4);
    int cnt = min(HTILE / 4, NNZ / 4 - base);
    for (int i = t; i < cnt; i += 256) {
        int4 r = row4[base + i];
        atomicAdd(&lh[wv][r.x >> 10], 1);
        atomicAdd(&lh[wv][r.y >> 10], 1);
        atomicAdd(&lh[wv][r.z >> 10], 1);
        atomicAdd(&lh[wv][r.w >> 10], 1);
    }
    __syncthreads();
    for (int i = t; i < NB; i += 256) {
        int s = lh[0][i] + lh[1][i] + lh[2][i] + lh[3][i];
        if (s) atomicAdd(&bhist[i], s);
    }
}

// parallel exclusive scan over NB (=147) entries, wave-shuffle based
__global__ void k_bucket_scan(const int* __restrict__ bhist, int* __restrict__ bbase,
                              int* __restrict__ bcur) {
    __shared__ int wsum[4];
    int t = threadIdx.x, lane = t & 63, wv = t >> 6;
    int v = (t < NB) ? bhist[t] : 0;
    int iv = v;
    for (int off = 1; off < 64; off <<= 1) {
        int u = __shfl_up(iv, off);
        if (lane >= off) iv += u;
    }
    if (lane == 63) wsum[wv] = iv;
    __syncthreads();
    int woff = 0;
    for (int w = 0; w < wv; ++w) woff += wsum[w];
    int ex = woff + iv - v;
    if (t < NB) { bbase[t] = ex; bcur[t] = ex; }
    if (t == NB - 1) bbase[NB] = ex + v;
}

// ---------------- phase A: LDS-staged partition into 147 buckets ------------
// 512 thr, 8 edges/thread, per-wave privatized hist (contention /8).
// tmp[p] = { (row_local<<18)|col , val_bits } grouped (unordered) by bucket
__global__ void k_partition(const int* __restrict__ row, const int* __restrict__ col,
                            const float* __restrict__ vals, int* __restrict__ bcur,
                            int2* __restrict__ tmp) {
    __shared__ int2 stage[TILE];                    // 32 KB
    __shared__ unsigned char stageB[TILE];          // 4 KB
    __shared__ int whist[8][NB];                    // per-wave hists
    __shared__ int cumw[8][NB];                     // per-wave exclusive bases
    __shared__ int scn[NB];
    __shared__ int gbase[NB];
    __shared__ int wsum[8];
    int t = threadIdx.x;
    int lane = t & 63, wv = t >> 6;                 // 8 waves
    for (int i = t; i < 8 * NB; i += 512) ((int*)whist)[i] = 0;
    __syncthreads();
    int base = blockIdx.x * TILE;
    int cnt = min(TILE, NNZ - base);

    int  myb[8];
    int  myslot[8];
    int2 myp[8];
#pragma unroll
    for (int j = 0; j < 8; ++j) {
        int i = t + j * 512;
        myb[j] = -1;
        if (i < cnt) {
            int e = base + i;
            int r = row[e];
            int b = r >> 10;
            myb[j] = b;
            myp[j] = make_int2(((r & (RPB - 1)) << 18) | col[e], __float_as_int(vals[e]));
            myslot[j] = atomicAdd(&whist[wv][b], 1);
        }
    }
    __syncthreads();
    // merge per-wave hists -> per-wave exclusive bases + bucket totals
    int v = 0;
    if (t < NB) {
        int run = 0;
#pragma unroll
        for (int w = 0; w < 8; ++w) {
            cumw[w][t] = run;
            run += whist[w][t];
        }
        v = run;
    }
    // wave-shuffle exclusive scan of bucket totals -> scn (waves 0-2 cover NB)
    int iv = v;
    for (int off = 1; off < 64; off <<= 1) {
        int u = __shfl_up(iv, off);
        if (lane >= off) iv += u;
    }
    if (lane == 63) wsum[wv] = iv;
    __syncthreads();
    int woff = 0;
    for (int w = 0; w < wv; ++w) woff += wsum[w];
    if (t < NB) scn[t] = woff + iv - v;
    if (t < NB && v > 0) gbase[t] = atomicAdd(&bcur[t], v);
    __syncthreads();
#pragma unroll
    for (int j = 0; j < 8; ++j) {
        if (myb[j] >= 0) {
            int b = myb[j];
            int pos = scn[b] + cumw[wv][b] + myslot[j];
            stage[pos] = myp[j];
            stageB[pos] = (unsigned char)b;
        }
    }
    __syncthreads();
    for (int i = t; i < cnt; i += 512) {
        int b = stageB[i];
        tmp[gbase[b] + (i - scn[b])] = stage[i];
    }
}

// ---------------- phase B: per-bucket exact CSR, 1024 thr -------------------
// pass 1: privatized x4 LDS row-hist; shuffle scan -> rp; pass 2: counting sort
__global__ void k_bucket_csr(const int* __restrict__ bbase, const int2* __restrict__ tmp,
                             int2* __restrict__ edges, int* __restrict__ rp) {
    __shared__ int ph[4][RPB];                      // 16 KB privatized hists
    __shared__ int lex[RPB];                        // global row cursors
    __shared__ int wsum[16];
    int b = blockIdx.x, t = threadIdx.x;            // 1024 threads, 16 waves
    int lane = t & 63, wv = t >> 6;
    int s0 = bbase[b], s1 = bbase[b + 1];
    int n = s1 - s0;
    for (int i = t; i < 4 * RPB; i += 1024) ((int*)ph)[i] = 0;
    __syncthreads();
    int cp = wv >> 2;                               // 4 waves per copy
    for (int i = t; i < n; i += 1024)
        atomicAdd(&ph[cp][(unsigned)tmp[s0 + i].x >> 18], 1);
    __syncthreads();
    int v = ph[0][t] + ph[1][t] + ph[2][t] + ph[3][t];
    int iv = v;
    for (int off = 1; off < 64; off <<= 1) {
        int u = __shfl_up(iv, off);
        if (lane >= off) iv += u;
    }
    if (lane == 63) wsum[wv] = iv;
    __syncthreads();
    int woff = 0;
    for (int w = 0; w < wv; ++w) woff += wsum[w];
    int excl = woff + iv - v;                       // exclusive prefix within bucket
    int r = b * RPB + t;
    if (r < N_NODES) rp[r] = s0 + excl;
    if (b == NB - 1 && t == 0) rp[N_NODES] = NNZ;
    lex[t] = s0 + excl;                             // global cursor
    __syncthreads();
    for (int i = t; i < n; i += 1024) {
        int2 p = tmp[s0 + i];
        int rl = (unsigned)p.x >> 18;
        int pos = atomicAdd(&lex[rl], 1);
        edges[pos] = make_int2(p.x & 0x3FFFF, p.y);
    }
}

// ---------------- pull SpMM, one wave per row, lane = dim, bf16 gather ------
// 16 gathers in flight per wave; edge loads are wave-uniform -> s_load path.
// Tail handled by one masked 16-chunk (col->0, val->0), never a serial loop.
__device__ __forceinline__ float row_dot(const int* __restrict__ rp,
                                         const int2* __restrict__ edges,
                                         const unsigned short* __restrict__ x,
                                         int wid, int lane) {
    int start = __builtin_amdgcn_readfirstlane(rp[wid]);
    int end   = __builtin_amdgcn_readfirstlane(rp[wid + 1]);
    float s0 = 0.f, s1 = 0.f, s2 = 0.f, s3 = 0.f;
    int e = start;
    for (; e + 16 <= end; e += 16) {
        int2 E[16];
#pragma unroll
        for (int j = 0; j < 16; ++j) E[j] = edges[e + j];
        float g[16];
#pragma unroll
        for (int j = 0; j < 16; ++j) g[j] = bf2f(x[(size_t)E[j].x * EMB_D + lane]);
#pragma unroll
        for (int j = 0; j < 16; ++j) {
            float p = __int_as_float(E[j].y) * g[j];
            if ((j & 3) == 0) s0 += p;
            else if ((j & 3) == 1) s1 += p;
            else if ((j & 3) == 2) s2 += p;
            else s3 += p;
        }
    }
    int rem = end - e;
    if (rem > 0) {
        // over-reads <=15 int2 past rp[N]; lands in allocated ws, masked below
        int2 E[16];
#pragma unroll
        for (int j = 0; j < 16; ++j) E[j] = edges[e + j];
#pragma unroll
        for (int j = 0; j < 16; ++j)
            if (j >= rem) { E[j].x = 0; E[j].y = 0; }
        float g[16];
#pragma unroll
        for (int j = 0; j < 16; ++j) g[j] = bf2f(x[(size_t)E[j].x * EMB_D + lane]);
#pragma unroll
        for (int j = 0; j < 16; ++j) {
            float p = __int_as_float(E[j].y) * g[j];
            if ((j & 3) == 0) s0 += p;
            else if ((j & 3) == 1) s1 += p;
            else if ((j & 3) == 2) s2 += p;
            else s3 += p;
        }
    }
    return (s0 + s1) + (s2 + s3);
}

// layers 1,2: y = bf16(spmm(x)) only
__global__ void k_spmm_mid(const int* __restrict__ rp, const int2* __restrict__ edges,
                           const unsigned short* __restrict__ x,
                           unsigned short* __restrict__ y) {
    int wid = blockIdx.x * (blockDim.x >> 6) + (threadIdx.x >> 6);
    if (wid >= N_NODES) return;
    int lane = threadIdx.x & 63;
    float s = row_dot(rp, edges, x, wid, lane);
    y[(size_t)wid * EMB_D + lane] = f2bf(s);
}

// layer 3: acc = (emb0 + y1 + y2 + s) * 0.25
__global__ void k_spmm_fin(const int* __restrict__ rp, const int2* __restrict__ edges,
                           const unsigned short* __restrict__ x,
                           const float* __restrict__ emb0,
                           const unsigned short* __restrict__ y1,
                           const unsigned short* __restrict__ y2,
                           float* __restrict__ acc) {
    int wid = blockIdx.x * (blockDim.x >> 6) + (threadIdx.x >> 6);
    if (wid >= N_NODES) return;
    int lane = threadIdx.x & 63;
    float s = row_dot(rp, edges, x, wid, lane);
    size_t o = (size_t)wid * EMB_D + lane;
    acc[o] = (emb0[o] + bf2f(y1[o]) + bf2f(y2[o]) + s) * 0.25f;
}

extern "C" void kernel_launch(void* const* d_in, const int* in_sizes, int n_in,
                              void* d_out, int out_size, void* d_ws, size_t ws_size,
                              hipStream_t stream) {
    const float* user_emb = (const float*)d_in[0];
    const float* item_emb = (const float*)d_in[1];
    const int*   row      = (const int*)d_in[2];
    const int*   col      = (const int*)d_in[3];
    const float* vals     = (const float*)d_in[4];

    float* emb0 = (float*)d_out;            // [ND] output 0
    float* acc  = (float*)d_out + ND;       // [ND] output 1

    // ws: [tmp int2[NNZ] | edges int2[NNZ] | hb2 ushort[ND] | ints]
    // tmp (38.4 MB) is dead after k_bucket_csr -> reused as hb0/hb1 bf16
    int2* tmp   = (int2*)d_ws;
    int2* edges = tmp + NNZ;
    unsigned short* hb2 = (unsigned short*)(edges + NNZ);   // [ND]
    int*  ibase = (int*)(hb2 + ND);
    int*  rp    = ibase;                     // [N_NODES+1]
    int*  bhist = ibase + N_NODES + 1;       // [NB]
    int*  bbase = bhist + NB;                // [NB+1]
    int*  bcur  = bbase + NB + 1;            // [NB]
    unsigned short* hb0 = (unsigned short*)d_ws;   // [ND] aliases tmp
    unsigned short* hb1 = hb0 + ND;                // [ND]

    const int BLK = 256;
    const int grid_nd = (ND4 + BLK - 1) / BLK;
    const int grid_spmm = (N_NODES * 64 + BLK - 1) / BLK;  // 1 wave per row

    // --- CSR build: hist -> scan -> partition -> per-bucket sort ---
    hipMemsetAsync(bhist, 0, NB * sizeof(int), stream);
    k_bucket_hist<<<NHT, BLK, 0, stream>>>((const int4*)row, bhist);
    k_bucket_scan<<<1, BLK, 0, stream>>>(bhist, bbase, bcur);
    k_partition<<<NTILE, 512, 0, stream>>>(row, col, vals, bcur, tmp);
    k_bucket_csr<<<NB, 1024, 0, stream>>>(bbase, tmp, edges, rp);

    // --- init outputs + bf16 layer-0 (overwrites tmp region) ---
    k_init<<<grid_nd, BLK, 0, stream>>>((const float4*)user_emb,
                                        (const float4*)item_emb,
                                        (float4*)emb0, (ushort4*)hb0);

    // --- 3 propagation layers, acc deferred to the final pass ---
    k_spmm_mid<<<grid_spmm, BLK, 0, stream>>>(rp, edges, hb0, hb1);
    k_spmm_mid<<<grid_spmm, BLK, 0, stream>>>(rp, edges, hb1, hb2);
    k_spmm_fin<<<grid_spmm, BLK, 0, stream>>>(rp, edges, hb2, emb0, hb1, hb2, acc);
}